// Round 1
// baseline (126.098 us; speedup 1.0000x reference)
//
#include <hip/hip_runtime.h>
#include <hip/hip_bf16.h>

// SoftRAM attention: S=128 seq, B=256 bits/token, H=16 heads, NB=12 bits/neuron,
// PB=7 rel-pos bits. addr decomposes as aq[i] | ak[j] | ap[i-j] (disjoint bit
// groups per (h,n) since connections are fixed per neuron). Only sign(memory)
// matters -> 512B bit-LUT per (h,n) in LDS.

#define S 128
#define B 256
#define H 16
#define NB 12

__global__ __launch_bounds__(512) void softram_kernel(
    const int* __restrict__ tokens,        // [S,B] 0/1
    const float* __restrict__ memory,      // [H,B,4096]
    const int* __restrict__ connections,   // [H,B,NB], values in [0,519)
    int* __restrict__ out)                 // [S,B] 0/1
{
    const int n = blockIdx.x;      // neuron column 0..255
    const int tid = threadIdx.x;   // 0..511

    __shared__ unsigned int   lut[H][128];      // 4096 sign bits per head: 8 KB
    __shared__ unsigned int   tok[S][8];        // packed token bits: 4 KB
    __shared__ unsigned short aqs[H][S];        // 4 KB
    __shared__ unsigned short aks[H][S];        // 4 KB
    __shared__ unsigned short aps[H][S];        // 4 KB
    __shared__ int            conns[H][NB];     // 768 B
    __shared__ unsigned short partial[8][S];    // 2 KB

    // ---- Phase B: LUT rows -> sign bits in LDS (the big HBM read) ----
    // 16 heads x 128 dwords = 2048 slots; 4 rounds of 512 threads.
    #pragma unroll
    for (int q = 0; q < 4; ++q) {
        int s = tid + (q << 9);
        int h = s >> 7;            // 0..15
        int d = s & 127;           // dword index within head's 4096-bit table
        const float4* mrow = (const float4*)(memory + (((size_t)((h << 8) | n)) << 12));
        unsigned int w = 0;
        #pragma unroll
        for (int t = 0; t < 8; ++t) {
            float4 v = mrow[(d << 3) + t];
            w |= (unsigned int)(v.x > 0.f) << (4 * t + 0);
            w |= (unsigned int)(v.y > 0.f) << (4 * t + 1);
            w |= (unsigned int)(v.z > 0.f) << (4 * t + 2);
            w |= (unsigned int)(v.w > 0.f) << (4 * t + 3);
        }
        lut[h][d] = w;
    }

    // ---- Phase A: pack tokens (128 rows x 8 dwords = 1024 slots, 2 rounds) ----
    #pragma unroll
    for (int q = 0; q < 2; ++q) {
        int e = tid + (q << 9);
        int i = e >> 3;
        int w = e & 7;
        const int4* tp = (const int4*)tokens;
        unsigned int v = 0;
        #pragma unroll
        for (int t = 0; t < 8; ++t) {
            int4 x = tp[i * 64 + w * 8 + t];
            v |= (unsigned int)(x.x & 1) << (4 * t + 0);
            v |= (unsigned int)(x.y & 1) << (4 * t + 1);
            v |= (unsigned int)(x.z & 1) << (4 * t + 2);
            v |= (unsigned int)(x.w & 1) << (4 * t + 3);
        }
        tok[i][w] = v;
    }

    // connections for this neuron column: conns[h][b]
    if (tid < H * NB) {
        int h = tid / NB;
        int b = tid - h * NB;
        conns[h][b] = connections[h * (B * NB) + n * NB + b];
    }

    __syncthreads();

    // ---- Phase C: build aq/ak/ap tables. 16 heads x 128 idx = 2048 entries ----
    // Branches on conns[h][b] are wave-uniform (h constant across a wave).
    #pragma unroll
    for (int q = 0; q < 4; ++q) {
        int e = tid + (q << 9);
        int h = e >> 7;
        int ii = e & 127;          // serves as i (aq), j (ak), rel (ap)
        unsigned int aq = 0, ak = 0, ap = 0;
        #pragma unroll
        for (int b = 0; b < NB; ++b) {
            int c = conns[h][b];
            if (c < 256) {
                aq |= ((tok[ii][c >> 5] >> (c & 31)) & 1u) << b;
            } else if (c < 512) {
                int c2 = c - 256;
                ak |= ((tok[ii][c2 >> 5] >> (c2 & 31)) & 1u) << b;
            } else {
                ap |= (unsigned int)((ii >> (c - 512)) & 1) << b;
            }
        }
        aqs[h][ii] = (unsigned short)aq;
        aks[h][ii] = (unsigned short)ak;
        aps[h][ii] = (unsigned short)ap;
    }

    __syncthreads();

    // ---- Phase D: main parity loop ----
    // 8 groups of 64 lanes; group g handles heads 2g, 2g+1.
    // Lane owns i0 = lane and i1 = 127-lane -> uniform 129-iteration loop.
    const int g    = tid >> 6;
    const int lane = tid & 63;
    const int i0 = lane;
    const int i1 = 127 - lane;
    int c0 = 0, c1 = 0;

    #pragma unroll
    for (int r = 0; r < 2; ++r) {
        const int h = (g << 1) | r;
        const unsigned int aq0 = aqs[h][i0];
        const unsigned int aq1 = aqs[h][i1];
        const unsigned short* __restrict__ akrow = &aks[h][0];
        const unsigned short* __restrict__ aprow = &aps[h][0];
        const unsigned int* __restrict__ lrow = &lut[h][0];
        unsigned int p0 = 0, p1 = 0;
        #pragma unroll 8
        for (int k = 0; k <= 128; ++k) {
            // first phase: i = i0, j = k          (k = 0..lane)
            // second phase: i = i1, j = k-lane-1  (k = lane+1..128)
            bool first = (k <= lane);
            int j   = first ? k : (k - lane - 1);
            int imj = first ? (lane - k) : (128 - k);   // i - j
            unsigned int aqv = first ? aq0 : aq1;
            unsigned int addr = aqv | (unsigned int)akrow[j] | (unsigned int)aprow[imj];
            unsigned int bit = (lrow[addr >> 5] >> (addr & 31)) & 1u;
            p0 ^= first ? bit : 0u;
            p1 ^= first ? 0u : bit;
        }
        c0 += (int)p0;
        c1 += (int)p1;
    }
    partial[g][i0] = (unsigned short)c0;
    partial[g][i1] = (unsigned short)c1;

    __syncthreads();

    // ---- Epilogue: majority vote across 16 heads (8 group-partials of 0..2) ----
    if (tid < S) {
        int tot = 0;
        #pragma unroll
        for (int gg = 0; gg < 8; ++gg) tot += partial[gg][tid];
        out[tid * B + n] = (tot > (H / 2)) ? 1 : 0;
    }
}

extern "C" void kernel_launch(void* const* d_in, const int* in_sizes, int n_in,
                              void* d_out, int out_size, void* d_ws, size_t ws_size,
                              hipStream_t stream) {
    const int*   tokens      = (const int*)d_in[0];
    const float* memory      = (const float*)d_in[1];
    const int*   connections = (const int*)d_in[2];
    int*         out         = (int*)d_out;
    (void)in_sizes; (void)n_in; (void)out_size; (void)d_ws; (void)ws_size;

    softram_kernel<<<B, 512, 0, stream>>>(tokens, memory, connections, out);
}

// Round 2
// 118.786 us; speedup vs baseline: 1.0616x; 1.0616x over previous
//
#include <hip/hip_runtime.h>
#include <hip/hip_bf16.h>

// SoftRAM attention: S=128 seq, B=256 bits/token, H=16 heads, NB=12 bits/neuron,
// PB=7 rel-pos bits. addr decomposes as aq[i] | ak[j] | ap[i-j] (disjoint bit
// groups per (h,n) since connections are fixed per neuron). Only sign(memory)
// matters -> 512B bit-LUT per (h,n) in LDS.
//
// R2: block 512 -> 1024 (16 waves, one head per 64-lane group). Grid stays 256
// (1 block/CU); occupancy 8 -> 16 waves/CU. Phase D per-wave trip count halves.

#define S 128
#define B 256
#define H 16
#define NB 12

__global__ __launch_bounds__(1024) void softram_kernel(
    const int* __restrict__ tokens,        // [S,B] 0/1
    const float* __restrict__ memory,      // [H,B,4096]
    const int* __restrict__ connections,   // [H,B,NB], values in [0,519)
    int* __restrict__ out)                 // [S,B] 0/1
{
    const int n = blockIdx.x;      // neuron column 0..255
    const int tid = threadIdx.x;   // 0..1023

    __shared__ unsigned int   lut[H][128];      // 4096 sign bits per head: 8 KB
    __shared__ unsigned int   tok[S][8];        // packed token bits: 4 KB
    __shared__ unsigned short aqs[H][S];        // 4 KB
    __shared__ unsigned short aks[H][S];        // 4 KB
    __shared__ unsigned short aps[H][S];        // 4 KB
    __shared__ int            conns[H][NB];     // 768 B
    __shared__ unsigned short partial[H][S];    // 4 KB

    // ---- Phase B: LUT rows -> sign bits in LDS (the big HBM read) ----
    // 16 heads x 128 dwords = 2048 slots; 2 rounds of 1024 threads.
    #pragma unroll
    for (int q = 0; q < 2; ++q) {
        int s = tid + (q << 10);
        int h = s >> 7;            // 0..15
        int d = s & 127;           // dword index within head's 4096-bit table
        const float4* mrow = (const float4*)(memory + (((size_t)((h << 8) | n)) << 12));
        unsigned int w = 0;
        #pragma unroll
        for (int t = 0; t < 8; ++t) {
            float4 v = mrow[(d << 3) + t];
            w |= (unsigned int)(v.x > 0.f) << (4 * t + 0);
            w |= (unsigned int)(v.y > 0.f) << (4 * t + 1);
            w |= (unsigned int)(v.z > 0.f) << (4 * t + 2);
            w |= (unsigned int)(v.w > 0.f) << (4 * t + 3);
        }
        lut[h][d] = w;
    }

    // ---- Phase A: pack tokens (128 rows x 8 dwords = 1024 slots, 1 round) ----
    {
        int i = tid >> 3;
        int w = tid & 7;
        const int4* tp = (const int4*)tokens;
        unsigned int v = 0;
        #pragma unroll
        for (int t = 0; t < 8; ++t) {
            int4 x = tp[i * 64 + w * 8 + t];
            v |= (unsigned int)(x.x & 1) << (4 * t + 0);
            v |= (unsigned int)(x.y & 1) << (4 * t + 1);
            v |= (unsigned int)(x.z & 1) << (4 * t + 2);
            v |= (unsigned int)(x.w & 1) << (4 * t + 3);
        }
        tok[i][w] = v;
    }

    // connections for this neuron column: conns[h][b]
    if (tid < H * NB) {
        int h = tid / NB;
        int b = tid - h * NB;
        conns[h][b] = connections[h * (B * NB) + n * NB + b];
    }

    __syncthreads();

    // ---- Phase C: build aq/ak/ap tables. 16 heads x 128 idx = 2048 entries ----
    // Branches on conns[h][b] are wave-uniform (h constant across a wave).
    #pragma unroll
    for (int q = 0; q < 2; ++q) {
        int e = tid + (q << 10);
        int h = e >> 7;
        int ii = e & 127;          // serves as i (aq), j (ak), rel (ap)
        unsigned int aq = 0, ak = 0, ap = 0;
        #pragma unroll
        for (int b = 0; b < NB; ++b) {
            int c = conns[h][b];
            if (c < 256) {
                aq |= ((tok[ii][c >> 5] >> (c & 31)) & 1u) << b;
            } else if (c < 512) {
                int c2 = c - 256;
                ak |= ((tok[ii][c2 >> 5] >> (c2 & 31)) & 1u) << b;
            } else {
                ap |= (unsigned int)((ii >> (c - 512)) & 1) << b;
            }
        }
        aqs[h][ii] = (unsigned short)aq;
        aks[h][ii] = (unsigned short)ak;
        aps[h][ii] = (unsigned short)ap;
    }

    __syncthreads();

    // ---- Phase D: main parity loop ----
    // 16 groups of 64 lanes; group g handles head g.
    // Lane owns i0 = lane and i1 = 127-lane -> uniform 129-iteration loop.
    const int h    = tid >> 6;
    const int lane = tid & 63;
    const int i0 = lane;
    const int i1 = 127 - lane;

    const unsigned int aq0 = aqs[h][i0];
    const unsigned int aq1 = aqs[h][i1];
    const unsigned short* __restrict__ akrow = &aks[h][0];
    const unsigned short* __restrict__ aprow = &aps[h][0];
    const unsigned int* __restrict__ lrow = &lut[h][0];
    unsigned int p0 = 0, p1 = 0;
    #pragma unroll 8
    for (int k = 0; k <= 128; ++k) {
        // first phase: i = i0, j = k          (k = 0..lane)
        // second phase: i = i1, j = k-lane-1  (k = lane+1..128)
        bool first = (k <= lane);
        int j   = first ? k : (k - lane - 1);
        int imj = first ? (lane - k) : (128 - k);   // i - j
        unsigned int aqv = first ? aq0 : aq1;
        unsigned int addr = aqv | (unsigned int)akrow[j] | (unsigned int)aprow[imj];
        unsigned int bit = (lrow[addr >> 5] >> (addr & 31)) & 1u;
        p0 ^= first ? bit : 0u;
        p1 ^= first ? 0u : bit;
    }
    partial[h][i0] = (unsigned short)p0;
    partial[h][i1] = (unsigned short)p1;

    __syncthreads();

    // ---- Epilogue: majority vote across 16 heads ----
    if (tid < S) {
        int tot = 0;
        #pragma unroll
        for (int hh = 0; hh < H; ++hh) tot += partial[hh][tid];
        out[tid * B + n] = (tot > (H / 2)) ? 1 : 0;
    }
}

extern "C" void kernel_launch(void* const* d_in, const int* in_sizes, int n_in,
                              void* d_out, int out_size, void* d_ws, size_t ws_size,
                              hipStream_t stream) {
    const int*   tokens      = (const int*)d_in[0];
    const float* memory      = (const float*)d_in[1];
    const int*   connections = (const int*)d_in[2];
    int*         out         = (int*)d_out;
    (void)in_sizes; (void)n_in; (void)out_size; (void)d_ws; (void)ws_size;

    softram_kernel<<<B, 1024, 0, stream>>>(tokens, memory, connections, out);
}